// Round 1
// baseline (7376.252 us; speedup 1.0000x reference)
//
#include <hip/hip_runtime.h>
#include <math.h>

// Problem constants (Qwen3-MoE layer, B=2 S=1024 D=2048 H=16 KVH=4 HD=128 E=64 K=8 F=768)
#define NB     2
#define SEQ    1024
#define TOKS   2048      // B*S
#define DMODEL 2048
#define NH     16
#define NKV    4
#define HDIM   128
#define NEXP   64
#define TOPK   8
#define FFD    768

typedef __attribute__((ext_vector_type(8))) short bf16x8;   // 8 bf16 = 4 VGPRs (MFMA A/B frag)
typedef __attribute__((ext_vector_type(4))) float f32x4;    // MFMA C/D frag

// split f32 -> bf16 hi + bf16 lo (a ~= hi + lo to ~2^-17 rel). Packs 2 elems per call.
__device__ __forceinline__ void split2(float a, float b, unsigned int& hp, unsigned int& lp) {
    unsigned int h, l;
    asm("v_cvt_pk_bf16_f32 %0, %1, %2" : "=v"(h) : "v"(a), "v"(b));
    float hf0 = __uint_as_float(h << 16);
    float hf1 = __uint_as_float(h & 0xffff0000u);
    float l0 = a - hf0, l1 = b - hf1;
    asm("v_cvt_pk_bf16_f32 %0, %1, %2" : "=v"(l) : "v"(l0), "v"(l1));
    hp = h; lp = l;
}

// ---------------- rmsnorm over D=2048 (block per token); optionally emits bf16 hi/lo planes ----
__global__ __launch_bounds__(256) void rmsnorm2048_kernel(const float* __restrict__ x,
                                                          const float* __restrict__ w,
                                                          float* __restrict__ out,
                                                          unsigned short* __restrict__ hi,
                                                          unsigned short* __restrict__ lo) {
    int t = blockIdx.x;
    const float* xr = x + (size_t)t * DMODEL;
    float* orow = out + (size_t)t * DMODEL;
    int tid = threadIdx.x;
    float4 a = ((const float4*)xr)[tid * 2];
    float4 b = ((const float4*)xr)[tid * 2 + 1];
    float ss = a.x*a.x + a.y*a.y + a.z*a.z + a.w*a.w
             + b.x*b.x + b.y*b.y + b.z*b.z + b.w*b.w;
    __shared__ float red[256];
    red[tid] = ss;
    __syncthreads();
    for (int s = 128; s > 0; s >>= 1) {
        if (tid < s) red[tid] += red[tid + s];
        __syncthreads();
    }
    float rs = rsqrtf(red[0] * (1.0f / DMODEL) + 1e-6f);
    float4 w0 = ((const float4*)w)[tid * 2];
    float4 w1 = ((const float4*)w)[tid * 2 + 1];
    float4 o0, o1;
    o0.x = a.x * rs * w0.x; o0.y = a.y * rs * w0.y; o0.z = a.z * rs * w0.z; o0.w = a.w * rs * w0.w;
    o1.x = b.x * rs * w1.x; o1.y = b.y * rs * w1.y; o1.z = b.z * rs * w1.z; o1.w = b.w * rs * w1.w;
    ((float4*)orow)[tid * 2] = o0;
    ((float4*)orow)[tid * 2 + 1] = o1;
    if (hi) {
        unsigned int h0, l0_, h1, l1_, h2, l2_, h3, l3_;
        split2(o0.x, o0.y, h0, l0_);
        split2(o0.z, o0.w, h1, l1_);
        split2(o1.x, o1.y, h2, l2_);
        split2(o1.z, o1.w, h3, l3_);
        size_t off = (size_t)t * DMODEL + (size_t)tid * 8;
        *(uint4*)(hi + off) = make_uint4(h0, h1, h2, h3);
        *(uint4*)(lo + off) = make_uint4(l0_, l1_, l2_, l3_);
    }
}

// ---------------- generic f32 GEMM: C = A[M,K] @ B[K,N] (+resid), 128x128x16 tile ----------------
__global__ __launch_bounds__(256) void gemm128_kernel(const float* __restrict__ A,
                                                      const float* __restrict__ Bm,
                                                      const float* __restrict__ resid,
                                                      float* __restrict__ C,
                                                      int M, int N, int K) {
    __shared__ float As[16][132];
    __shared__ float Bs[16][132];
    int tid = threadIdx.x;
    int bm = blockIdx.y * 128, bn = blockIdx.x * 128;
    int tx = tid & 15, ty = tid >> 4;
    float acc[8][8];
#pragma unroll
    for (int i = 0; i < 8; ++i)
#pragma unroll
        for (int j = 0; j < 8; ++j) acc[i][j] = 0.f;

    int arow = tid >> 1, acol = (tid & 1) * 8;
    int brow = tid >> 4, bcol = (tid & 15) * 8;
    const float* Aptr = A + (size_t)(bm + arow) * K + acol;
    const float* Bptr = Bm + (size_t)brow * N + bn + bcol;

    for (int k0 = 0; k0 < K; k0 += 16) {
        float4 a0 = *(const float4*)(Aptr + k0);
        float4 a1 = *(const float4*)(Aptr + k0 + 4);
        As[acol + 0][arow] = a0.x; As[acol + 1][arow] = a0.y;
        As[acol + 2][arow] = a0.z; As[acol + 3][arow] = a0.w;
        As[acol + 4][arow] = a1.x; As[acol + 5][arow] = a1.y;
        As[acol + 6][arow] = a1.z; As[acol + 7][arow] = a1.w;
        const float* bp = Bptr + (size_t)k0 * N;
        *(float4*)&Bs[brow][bcol]     = *(const float4*)bp;
        *(float4*)&Bs[brow][bcol + 4] = *(const float4*)(bp + 4);
        __syncthreads();
#pragma unroll
        for (int k = 0; k < 16; ++k) {
            float a[8], b[8];
#pragma unroll
            for (int i = 0; i < 8; ++i) a[i] = As[k][ty * 8 + i];
#pragma unroll
            for (int j = 0; j < 8; ++j) b[j] = Bs[k][tx * 8 + j];
#pragma unroll
            for (int i = 0; i < 8; ++i)
#pragma unroll
                for (int j = 0; j < 8; ++j) acc[i][j] += a[i] * b[j];
        }
        __syncthreads();
    }
#pragma unroll
    for (int i = 0; i < 8; ++i) {
        size_t rowoff = (size_t)(bm + ty * 8 + i) * N + bn + tx * 8;
        float4 c0 = make_float4(acc[i][0], acc[i][1], acc[i][2], acc[i][3]);
        float4 c1 = make_float4(acc[i][4], acc[i][5], acc[i][6], acc[i][7]);
        if (resid) {
            float4 r0 = *(const float4*)(resid + rowoff);
            float4 r1 = *(const float4*)(resid + rowoff + 4);
            c0.x += r0.x; c0.y += r0.y; c0.z += r0.z; c0.w += r0.w;
            c1.x += r1.x; c1.y += r1.y; c1.z += r1.z; c1.w += r1.w;
        }
        *(float4*)(C + rowoff) = c0;
        *(float4*)(C + rowoff + 4) = c1;
    }
}

// ---------------- per-head q/k rmsnorm + RoPE, in place ----------------
__global__ __launch_bounds__(128) void qknorm_rope_kernel(float* __restrict__ q, float* __restrict__ kbuf,
                                                          const float* __restrict__ qn_w,
                                                          const float* __restrict__ kn_w,
                                                          const float* __restrict__ cosb,
                                                          const float* __restrict__ sinb) {
    int t = blockIdx.x;
    int head = blockIdx.y;
    int d = threadIdx.x;
    float* buf; const float* w;
    if (head < NH) { buf = q + ((size_t)t * NH + head) * HDIM; w = qn_w; }
    else           { buf = kbuf + ((size_t)t * NKV + (head - NH)) * HDIM; w = kn_w; }
    float v = buf[d];
    __shared__ float red[128];
    __shared__ float nb[128];
    red[d] = v * v;
    __syncthreads();
    for (int s = 64; s > 0; s >>= 1) { if (d < s) red[d] += red[d + s]; __syncthreads(); }
    float rs = rsqrtf(red[0] * (1.0f / HDIM) + 1e-6f);
    float n = v * rs * w[d];
    nb[d] = n;
    __syncthreads();
    float rh = (d < 64) ? -nb[d + 64] : nb[d - 64];
    float c  = cosb[(size_t)t * HDIM + d];
    float s2 = sinb[(size_t)t * HDIM + d];
    buf[d] = n * c + rh * s2;
}

// ---------------- flash attention (causal, GQA 16q/4kv), block = (b,h, 32 q rows) ----------------
__global__ __launch_bounds__(256) void attn_kernel(const float* __restrict__ q,
                                                   const float* __restrict__ kb,
                                                   const float* __restrict__ vb,
                                                   float* __restrict__ o) {
    int bh = blockIdx.x;
    int b = bh >> 4, hh = bh & 15;
    int kvh = hh >> 2;
    int qt = blockIdx.y;
    int m0 = qt * 32;
    int tid = threadIdx.x;
    __shared__ float Qs[32][132];
    __shared__ float Ks[32][132];
    __shared__ float Vs[32][132];
    __shared__ float Ss[32][33];
    __shared__ float rowm[32], rowl[32], rowa[32];
    const float scale = 0.08838834764831845f;

    int lr = tid >> 3, lc = (tid & 7) * 16;
    {
        const float* src = q + (((size_t)(b * SEQ + m0 + lr)) * NH + hh) * HDIM + lc;
#pragma unroll
        for (int p = 0; p < 4; ++p) {
            float4 v4 = *(const float4*)(src + p * 4);
            Qs[lr][lc + p * 4 + 0] = v4.x * scale;
            Qs[lr][lc + p * 4 + 1] = v4.y * scale;
            Qs[lr][lc + p * 4 + 2] = v4.z * scale;
            Qs[lr][lc + p * 4 + 3] = v4.w * scale;
        }
    }
    if (tid < 32) { rowm[tid] = -1e30f; rowl[tid] = 0.f; }
    float oacc[16];
#pragma unroll
    for (int j = 0; j < 16; ++j) oacc[j] = 0.f;
    int mrow = tid & 31, dbase = (tid >> 5) * 16;
    int mi = tid >> 3, kbase = (tid & 7) * 4;
    __syncthreads();

    for (int kt = 0; kt <= qt; ++kt) {
        int k0 = kt * 32;
        {
            const float* ksrc = kb + (((size_t)(b * SEQ + k0 + lr)) * NKV + kvh) * HDIM + lc;
            const float* vsrc = vb + (((size_t)(b * SEQ + k0 + lr)) * NKV + kvh) * HDIM + lc;
#pragma unroll
            for (int p = 0; p < 4; ++p) {
                *(float4*)&Ks[lr][lc + p * 4] = *(const float4*)(ksrc + p * 4);
                *(float4*)&Vs[lr][lc + p * 4] = *(const float4*)(vsrc + p * 4);
            }
        }
        __syncthreads();
        float sc[4] = {0.f, 0.f, 0.f, 0.f};
#pragma unroll 8
        for (int d4 = 0; d4 < 32; ++d4) {
            float4 qv = *(const float4*)&Qs[mi][d4 * 4];
#pragma unroll
            for (int i = 0; i < 4; ++i) {
                float4 kv = *(const float4*)&Ks[kbase + i][d4 * 4];
                sc[i] += qv.x * kv.x + qv.y * kv.y + qv.z * kv.z + qv.w * kv.w;
            }
        }
#pragma unroll
        for (int i = 0; i < 4; ++i) {
            int kg = k0 + kbase + i;
            Ss[mi][kbase + i] = (kg <= m0 + mi) ? sc[i] : -1e30f;
        }
        __syncthreads();
        if (tid < 32) {
            float mold = rowm[tid];
            float tm = mold;
            for (int j = 0; j < 32; ++j) tm = fmaxf(tm, Ss[tid][j]);
            float al = __expf(mold - tm);
            float sum = 0.f;
            for (int j = 0; j < 32; ++j) {
                float p = __expf(Ss[tid][j] - tm);
                Ss[tid][j] = p;
                sum += p;
            }
            rowa[tid] = al; rowm[tid] = tm;
            rowl[tid] = rowl[tid] * al + sum;
        }
        __syncthreads();
        float al = rowa[mrow];
#pragma unroll
        for (int j = 0; j < 16; ++j) oacc[j] *= al;
        for (int kk = 0; kk < 32; ++kk) {
            float p = Ss[mrow][kk];
            const float* vrow = &Vs[kk][dbase];
#pragma unroll
            for (int j = 0; j < 16; ++j) oacc[j] += p * vrow[j];
        }
        __syncthreads();
    }
    float linv = 1.0f / rowl[mrow];
    float* dst = o + ((size_t)(b * SEQ + m0 + mrow)) * DMODEL + hh * HDIM + dbase;
#pragma unroll
    for (int p = 0; p < 4; ++p) {
        float4 v4 = make_float4(oacc[p * 4 + 0] * linv, oacc[p * 4 + 1] * linv,
                                oacc[p * 4 + 2] * linv, oacc[p * 4 + 3] * linv);
        *(float4*)(dst + p * 4) = v4;
    }
}

// ---------------- router logits: block per token, thread per expert ----------------
__global__ __launch_bounds__(64) void router_kernel(const float* __restrict__ ht,
                                                    const float* __restrict__ rw,
                                                    float* __restrict__ logits) {
    int t = blockIdx.x; int e = threadIdx.x;
    const float* hrow = ht + (size_t)t * DMODEL;
    float acc = 0.f;
    for (int d = 0; d < DMODEL; ++d) acc = fmaf(hrow[d], rw[(size_t)d * NEXP + e], acc);
    logits[(size_t)t * NEXP + e] = acc;
}

// ---------------- top-8 in logit space (softmax Z cancels after renorm) ----------------
__global__ __launch_bounds__(64) void topk_kernel(const float* __restrict__ logits,
                                                  float* __restrict__ topw,
                                                  int* __restrict__ topi) {
    int t = blockIdx.x; int lane = threadIdx.x;
    float v = logits[(size_t)t * NEXP + lane];
    float mx = v;
#pragma unroll
    for (int off = 32; off; off >>= 1) mx = fmaxf(mx, __shfl_xor(mx, off));
    float myv = v;
    float sel_v[TOPK]; int sel_i[TOPK];
#pragma unroll
    for (int it = 0; it < TOPK; ++it) {
        float bv = myv; int bi = lane;
#pragma unroll
        for (int off = 32; off; off >>= 1) {
            float ov = __shfl_xor(bv, off);
            int oi = __shfl_xor(bi, off);
            if (ov > bv || (ov == bv && oi < bi)) { bv = ov; bi = oi; }
        }
        sel_v[it] = bv; sel_i[it] = bi;
        if (lane == bi) myv = -3e38f;
    }
    float sum = 0.f;
#pragma unroll
    for (int it = 0; it < TOPK; ++it) sum += __expf(sel_v[it] - mx);
    if (lane == 0) {
#pragma unroll
        for (int it = 0; it < TOPK; ++it) {
            topw[(size_t)t * TOPK + it] = __expf(sel_v[it] - mx) / sum;
            topi[(size_t)t * TOPK + it] = sel_i[it];
        }
    }
}

// ---------------- routing bookkeeping ----------------
__global__ void zero_small_kernel(int* cnt, int* pos) {
    int i = threadIdx.x;
    if (i < NEXP) { cnt[i] = 0; pos[i] = 0; }
}
__global__ void hist_kernel(const int* __restrict__ topi, int* __restrict__ cnt) {
    int i = blockIdx.x * 256 + threadIdx.x;
    if (i < TOKS * TOPK) atomicAdd(&cnt[topi[i]], 1);
}
__global__ void scan_kernel(const int* __restrict__ cnt, int* __restrict__ eoff) {
    if (threadIdx.x == 0) {
        int a = 0;
        for (int e = 0; e < NEXP; ++e) { eoff[e] = a; a += cnt[e]; }
    }
}
__global__ void scatter_kernel(const int* __restrict__ topi, const float* __restrict__ topw,
                               const int* __restrict__ eoff, int* __restrict__ pos,
                               int* __restrict__ tokl, float* __restrict__ wtl) {
    int i = blockIdx.x * 256 + threadIdx.x;
    if (i >= TOKS * TOPK) return;
    int e = topi[i];
    int slot = atomicAdd(&pos[e], 1);
    int idx = eoff[e] + slot;
    tokl[idx] = i >> 3;
    wtl[idx] = topw[i];
}

// LDS layout for bf16 tiles: [64 rows][4 k-chunks of 8 bf16 + 8 pad] stride 40 ushorts (80B).
// chunk slot XOR-swizzled by (row>>3)&3 to spread the b128/b64 write pattern across banks.
#define LROW 40
__device__ __forceinline__ int lds_off(int row, int kc) {
    return row * LROW + (((kc ^ (row >> 3)) & 3) << 3);   // ushort index, 16B aligned
}

// ---------------- MoE phase A (MFMA bf16x3): act = silu(ht@wg)*(ht@wu)*wt ----------------
// tile 64(rows) x 64(F), 4 waves 2x2, each wave 2x2 frags of mfma_f32_16x16x32_bf16, K-step 32
__global__ __launch_bounds__(256) void moe_gateup_mfma(
        const unsigned short* __restrict__ hthi, const unsigned short* __restrict__ htlo,
        const float* __restrict__ wg, const float* __restrict__ wu,
        const int* __restrict__ tokl, const float* __restrict__ wtl,
        const int* __restrict__ eoff, const int* __restrict__ ecnt,
        unsigned short* __restrict__ acthi, unsigned short* __restrict__ actlo) {
    int mt = blockIdx.x, ft = blockIdx.y, e = blockIdx.z;   // mt fastest: weight panel stays L2-hot
    int ne = ecnt[e];
    int r0 = mt * 64;
    if (r0 >= ne) return;
    int base = eoff[e];
    int tid = threadIdx.x;

    __shared__ __align__(16) unsigned short Ah[64 * LROW], Al[64 * LROW];
    __shared__ __align__(16) unsigned short Gh[64 * LROW], Gl[64 * LROW];
    __shared__ __align__(16) unsigned short Uh[64 * LROW], Ul[64 * LROW];

    // A staging: thread -> (row, k-chunk of 8)
    int arow = tid >> 2, akc = tid & 3;
    const unsigned short* ahsrc = nullptr;
    const unsigned short* alsrc = nullptr;
    if (r0 + arow < ne) {
        size_t o = (size_t)tokl[base + r0 + arow] * DMODEL + akc * 8;
        ahsrc = hthi + o;
        alsrc = htlo + o;
    }
    // B staging: thread -> (n col, k-chunk of 8); loads are lane-coalesced along n
    int bn = tid & 63, bkc = tid >> 6;
    const float* wgp = wg + (size_t)e * DMODEL * FFD + (size_t)ft * 64 + bn;
    const float* wup = wu + (size_t)e * DMODEL * FFD + (size_t)ft * 64 + bn;

    int lane = tid & 63, wave = tid >> 6;
    int wr = wave >> 1, wc = wave & 1;
    int lrow = lane & 15, lkc = lane >> 4;

    f32x4 z4 = {0.f, 0.f, 0.f, 0.f};
    f32x4 accG[2][2], accU[2][2];
#pragma unroll
    for (int m = 0; m < 2; ++m)
#pragma unroll
        for (int n = 0; n < 2; ++n) { accG[m][n] = z4; accU[m][n] = z4; }

    int aoff[2], boff[2];
#pragma unroll
    for (int m = 0; m < 2; ++m) aoff[m] = lds_off(wr * 32 + m * 16 + lrow, lkc);
#pragma unroll
    for (int n = 0; n < 2; ++n) boff[n] = lds_off(wc * 32 + n * 16 + lrow, lkc);
    int awoff = lds_off(arow, akc);
    int bwoff = lds_off(bn, bkc);

    const bf16x8 zero8 = {0, 0, 0, 0, 0, 0, 0, 0};

    for (int k0 = 0; k0 < DMODEL; k0 += 32) {
        bf16x8 avh = ahsrc ? *(const bf16x8*)(ahsrc + k0) : zero8;
        bf16x8 avl = alsrc ? *(const bf16x8*)(alsrc + k0) : zero8;
        float gv[8], uv[8];
#pragma unroll
        for (int j = 0; j < 8; ++j) {
            size_t ro = (size_t)(k0 + bkc * 8 + j) * FFD;
            gv[j] = wgp[ro];
            uv[j] = wup[ro];
        }
        unsigned int ghp[4], glp[4], uhp[4], ulp[4];
#pragma unroll
        for (int p = 0; p < 4; ++p) {
            split2(gv[2 * p], gv[2 * p + 1], ghp[p], glp[p]);
            split2(uv[2 * p], uv[2 * p + 1], uhp[p], ulp[p]);
        }
        __syncthreads();
        *(bf16x8*)(Ah + awoff) = avh;
        *(bf16x8*)(Al + awoff) = avl;
        *(uint4*)(Gh + bwoff) = make_uint4(ghp[0], ghp[1], ghp[2], ghp[3]);
        *(uint4*)(Gl + bwoff) = make_uint4(glp[0], glp[1], glp[2], glp[3]);
        *(uint4*)(Uh + bwoff) = make_uint4(uhp[0], uhp[1], uhp[2], uhp[3]);
        *(uint4*)(Ul + bwoff) = make_uint4(ulp[0], ulp[1], ulp[2], ulp[3]);
        __syncthreads();

        bf16x8 a_h[2], a_l[2];
#pragma unroll
        for (int m = 0; m < 2; ++m) {
            a_h[m] = *(const bf16x8*)(Ah + aoff[m]);
            a_l[m] = *(const bf16x8*)(Al + aoff[m]);
        }
#pragma unroll
        for (int n = 0; n < 2; ++n) {
            bf16x8 g_h = *(const bf16x8*)(Gh + boff[n]);
            bf16x8 g_l = *(const bf16x8*)(Gl + boff[n]);
            bf16x8 u_h = *(const bf16x8*)(Uh + boff[n]);
            bf16x8 u_l = *(const bf16x8*)(Ul + boff[n]);
#pragma unroll
            for (int m = 0; m < 2; ++m) {
                accG[m][n] = __builtin_amdgcn_mfma_f32_16x16x32_bf16(a_h[m], g_h, accG[m][n], 0, 0, 0);
                accG[m][n] = __builtin_amdgcn_mfma_f32_16x16x32_bf16(a_l[m], g_h, accG[m][n], 0, 0, 0);
                accG[m][n] = __builtin_amdgcn_mfma_f32_16x16x32_bf16(a_h[m], g_l, accG[m][n], 0, 0, 0);
                accU[m][n] = __builtin_amdgcn_mfma_f32_16x16x32_bf16(a_h[m], u_h, accU[m][n], 0, 0, 0);
                accU[m][n] = __builtin_amdgcn_mfma_f32_16x16x32_bf16(a_l[m], u_h, accU[m][n], 0, 0, 0);
                accU[m][n] = __builtin_amdgcn_mfma_f32_16x16x32_bf16(a_h[m], u_l, accU[m][n], 0, 0, 0);
            }
        }
    }

    // epilogue: C/D layout col=lane&15, row=(lane>>4)*4+r  (guide-verified)
    int crow4 = (lane >> 4) * 4;
#pragma unroll
    for (int m = 0; m < 2; ++m)
#pragma unroll
        for (int r = 0; r < 4; ++r) {
            int gr = r0 + wr * 32 + m * 16 + crow4 + r;
            if (gr < ne) {
                float wt = wtl[base + gr];
                size_t rowoff = (size_t)(base + gr) * FFD + ft * 64 + wc * 32 + lrow;
                float g0 = accG[m][0][r], g1 = accG[m][1][r];
                float u0 = accU[m][0][r], u1 = accU[m][1][r];
                float x0 = g0 / (1.f + __expf(-g0)) * u0 * wt;
                float x1 = g1 / (1.f + __expf(-g1)) * u1 * wt;
                unsigned int hp, lp;
                split2(x0, x1, hp, lp);
                acthi[rowoff]      = (unsigned short)(hp & 0xffffu);
                acthi[rowoff + 16] = (unsigned short)(hp >> 16);
                actlo[rowoff]      = (unsigned short)(lp & 0xffffu);
                actlo[rowoff + 16] = (unsigned short)(lp >> 16);
            }
        }
}

// ---------------- MoE phase B (MFMA bf16x3): out[tok] += act @ wd ----------------
__global__ __launch_bounds__(256) void moe_down_mfma(
        const unsigned short* __restrict__ acthi, const unsigned short* __restrict__ actlo,
        const float* __restrict__ wd,
        const int* __restrict__ tokl, const int* __restrict__ eoff, const int* __restrict__ ecnt,
        float* __restrict__ out) {
    int mt = blockIdx.x, dt = blockIdx.y, e = blockIdx.z;
    int ne = ecnt[e];
    int r0 = mt * 64;
    if (r0 >= ne) return;
    int base = eoff[e];
    int tid = threadIdx.x;

    __shared__ __align__(16) unsigned short Ah[64 * LROW], Al[64 * LROW];
    __shared__ __align__(16) unsigned short Wh[64 * LROW], Wl[64 * LROW];

    int arow = tid >> 2, akc = tid & 3;
    const unsigned short* ahsrc = nullptr;
    const unsigned short* alsrc = nullptr;
    if (r0 + arow < ne) {
        size_t o = (size_t)(base + r0 + arow) * FFD + akc * 8;
        ahsrc = acthi + o;
        alsrc = actlo + o;
    }
    int bn = tid & 63, bkc = tid >> 6;
    const float* wdp = wd + (size_t)e * FFD * DMODEL + (size_t)dt * 64 + bn;

    int lane = tid & 63, wave = tid >> 6;
    int wr = wave >> 1, wc = wave & 1;
    int lrow = lane & 15, lkc = lane >> 4;

    f32x4 z4 = {0.f, 0.f, 0.f, 0.f};
    f32x4 acc[2][2];
#pragma unroll
    for (int m = 0; m < 2; ++m)
#pragma unroll
        for (int n = 0; n < 2; ++n) acc[m][n] = z4;

    int aoff[2], boff[2];
#pragma unroll
    for (int m = 0; m < 2; ++m) aoff[m] = lds_off(wr * 32 + m * 16 + lrow, lkc);
#pragma unroll
    for (int n = 0; n < 2; ++n) boff[n] = lds_off(wc * 32 + n * 16 + lrow, lkc);
    int awoff = lds_off(arow, akc);
    int bwoff = lds_off(bn, bkc);

    const bf16x8 zero8 = {0, 0, 0, 0, 0, 0, 0, 0};

    for (int k0 = 0; k0 < FFD; k0 += 32) {
        bf16x8 avh = ahsrc ? *(const bf16x8*)(ahsrc + k0) : zero8;
        bf16x8 avl = alsrc ? *(const bf16x8*)(alsrc + k0) : zero8;
        float wv[8];
#pragma unroll
        for (int j = 0; j < 8; ++j) wv[j] = wdp[(size_t)(k0 + bkc * 8 + j) * DMODEL];
        unsigned int whp[4], wlp[4];
#pragma unroll
        for (int p = 0; p < 4; ++p) split2(wv[2 * p], wv[2 * p + 1], whp[p], wlp[p]);
        __syncthreads();
        *(bf16x8*)(Ah + awoff) = avh;
        *(bf16x8*)(Al + awoff) = avl;
        *(uint4*)(Wh + bwoff) = make_uint4(whp[0], whp[1], whp[2], whp[3]);
        *(uint4*)(Wl + bwoff) = make_uint4(wlp[0], wlp[1], wlp[2], wlp[3]);
        __syncthreads();

        bf16x8 a_h[2], a_l[2];
#pragma unroll
        for (int m = 0; m < 2; ++m) {
            a_h[m] = *(const bf16x8*)(Ah + aoff[m]);
            a_l[m] = *(const bf16x8*)(Al + aoff[m]);
        }
#pragma unroll
        for (int n = 0; n < 2; ++n) {
            bf16x8 w_h = *(const bf16x8*)(Wh + boff[n]);
            bf16x8 w_l = *(const bf16x8*)(Wl + boff[n]);
#pragma unroll
            for (int m = 0; m < 2; ++m) {
                acc[m][n] = __builtin_amdgcn_mfma_f32_16x16x32_bf16(a_h[m], w_h, acc[m][n], 0, 0, 0);
                acc[m][n] = __builtin_amdgcn_mfma_f32_16x16x32_bf16(a_l[m], w_h, acc[m][n], 0, 0, 0);
                acc[m][n] = __builtin_amdgcn_mfma_f32_16x16x32_bf16(a_h[m], w_l, acc[m][n], 0, 0, 0);
            }
        }
    }

    int crow4 = (lane >> 4) * 4;
#pragma unroll
    for (int m = 0; m < 2; ++m)
#pragma unroll
        for (int r = 0; r < 4; ++r) {
            int gr = r0 + wr * 32 + m * 16 + crow4 + r;
            if (gr < ne) {
                int tok = tokl[base + gr];
                float* dst = out + (size_t)tok * DMODEL + dt * 64 + wc * 32 + lrow;
                atomicAdd(dst, acc[m][0][r]);
                atomicAdd(dst + 16, acc[m][1][r]);
            }
        }
}

extern "C" void kernel_launch(void* const* d_in, const int* in_sizes, int n_in,
                              void* d_out, int out_size, void* d_ws, size_t ws_size,
                              hipStream_t stream) {
    const float* x    = (const float*)d_in[0];
    const float* cosb = (const float*)d_in[1];
    const float* sinb = (const float*)d_in[2];
    const float* ln1  = (const float*)d_in[3];
    const float* wq   = (const float*)d_in[4];
    const float* wk   = (const float*)d_in[5];
    const float* wv   = (const float*)d_in[6];
    const float* wo   = (const float*)d_in[7];
    const float* qnw  = (const float*)d_in[8];
    const float* knw  = (const float*)d_in[9];
    const float* ln2  = (const float*)d_in[10];
    const float* rw   = (const float*)d_in[11];
    const float* wg   = (const float*)d_in[12];
    const float* wu   = (const float*)d_in[13];
    const float* wd   = (const float*)d_in[14];
    float* out = (float*)d_out;

    // workspace layout (floats); total ~93 MB (unchanged footprint)
    float* ws     = (float*)d_ws;
    float* h      = ws;                       // 4194304  (rmsnorm1 out; reused as attn_o, then ht hi/lo planes)
    float* qb     = h + 4194304;              // 4194304  (q; reused as ht)
    float* kbuf   = qb + 4194304;             // 1048576
    float* vbuf   = kbuf + 1048576;           // 1048576
    float* act    = vbuf + 1048576;           // 12582912 floats -> two ushort planes (hi/lo), same bytes
    float* logits = act + 12582912;           // 131072
    float* topw   = logits + 131072;          // 16384
    float* wtl    = topw + 16384;             // 16384
    int* topi     = (int*)(wtl + 16384);      // 16384
    int* tokl     = topi + 16384;             // 16384
    int* cnt      = tokl + 16384;             // 64
    int* eoff     = cnt + 64;                 // 64
    int* pos      = eoff + 64;                // 64
    float* attn_o = h;                        // alias: h dead after QKV gemms
    float* ht     = qb;                       // alias: q dead after attention

    unsigned short* acthi = (unsigned short*)act;                    // 16384*768 ushorts
    unsigned short* actlo = acthi + (size_t)16384 * FFD;             // 16384*768 ushorts
    unsigned short* hthi  = (unsigned short*)h;                      // 2048*2048 ushorts (h dead after wo gemm)
    unsigned short* htlo  = hthi + (size_t)TOKS * DMODEL;            // 2048*2048 ushorts

    rmsnorm2048_kernel<<<TOKS, 256, 0, stream>>>(x, ln1, h, nullptr, nullptr);
    gemm128_kernel<<<dim3(16, 16), 256, 0, stream>>>(h, wq, nullptr, qb, TOKS, 2048, DMODEL);
    gemm128_kernel<<<dim3(4, 16), 256, 0, stream>>>(h, wk, nullptr, kbuf, TOKS, 512, DMODEL);
    gemm128_kernel<<<dim3(4, 16), 256, 0, stream>>>(h, wv, nullptr, vbuf, TOKS, 512, DMODEL);
    qknorm_rope_kernel<<<dim3(TOKS, NH + NKV), 128, 0, stream>>>(qb, kbuf, qnw, knw, cosb, sinb);
    attn_kernel<<<dim3(NB * NH, SEQ / 32), 256, 0, stream>>>(qb, kbuf, vbuf, attn_o);
    gemm128_kernel<<<dim3(16, 16), 256, 0, stream>>>(attn_o, wo, x, out, TOKS, 2048, DMODEL);
    rmsnorm2048_kernel<<<TOKS, 256, 0, stream>>>(out, ln2, ht, hthi, htlo);
    router_kernel<<<TOKS, 64, 0, stream>>>(ht, rw, logits);
    topk_kernel<<<TOKS, 64, 0, stream>>>(logits, topw, topi);
    zero_small_kernel<<<1, 64, 0, stream>>>(cnt, pos);
    hist_kernel<<<64, 256, 0, stream>>>(topi, cnt);
    scan_kernel<<<1, 1, 0, stream>>>(cnt, eoff);
    scatter_kernel<<<64, 256, 0, stream>>>(topi, topw, eoff, pos, tokl, wtl);
    moe_gateup_mfma<<<dim3(32, FFD / 64, NEXP), 256, 0, stream>>>(hthi, htlo, wg, wu, tokl, wtl, eoff, cnt, acthi, actlo);
    moe_down_mfma<<<dim3(32, DMODEL / 64, NEXP), 256, 0, stream>>>(acthi, actlo, wd, tokl, eoff, cnt, out);
}